// Round 24
// baseline (113.549 us; speedup 1.0000x reference)
//
#include <hip/hip_runtime.h>
#include <math.h>

#define D 64
#define K 512
#define N_TOK (32 * 4096)            // 131072 tokens
#define SBLK 512                     // screen threads (8 waves)
#define TPB 256                      // tokens per block (8 waves x 32)
#define EPS 1e-5f                    // screen ambiguity margin (err bound ~5e-7, 20x)
#define FLAG_CAP 8192
#define RBLKS 1024                   // refine grid (last block runs fin)

// output layout (all f32, concatenated in reference return order)
#define Q_OFF    0
#define LOSS_OFF 8388608
#define PERP_OFF 8388609
#define ENC_OFF  8388610
#define MIND_OFF 8519682

// ws layout (floats): [0..511] b2 ; [512] S ; [514..1025] counts(int) ;
// [1026] nflag(int) ; [1027] ticket(int) ; [1028..1028+FLAG_CAP) flist(int) ;
// [16384..] bf16 codebook image, 65536 shorts = 128 KB (ws >= 192 KB).
// img: chunk c (32 codes) = 512 slots x 16B, slot s = grp*64 + lane,
//   grp = plane*4 + f*2 + sub; slot holds codes k=c*32+sub*16+(lane&15),
//   dims f*32+(lane>>4)*8 .. +8, hi (plane0) or lo (plane1) bf16.

typedef __attribute__((ext_vector_type(8))) short  short8;   // 8 bf16 (4 VGPR)
typedef __attribute__((ext_vector_type(4))) float  f32x4;

__device__ __forceinline__ short f2bf(float x) {             // RNE f32->bf16 bits
    unsigned u = __builtin_bit_cast(unsigned, x);
    unsigned r = (u + 0x7fffu + ((u >> 16) & 1u)) >> 16;
    return (short)r;
}
__device__ __forceinline__ float bf2f(short s) {
    unsigned u = ((unsigned)(unsigned short)s) << 16;
    return __builtin_bit_cast(float, u);
}
__device__ __forceinline__ f32x4 mfma16(short8 a, short8 b, f32x4 c) {
    return __builtin_amdgcn_mfma_f32_16x16x32_bf16(a, b, c, 0, 0, 0);
}

// numpy pairwise_sum, n=64, scalar 8-accumulator order on fl(x*x)
__device__ __forceinline__ float np_sumsq64(const float* x) {
    float r[8];
    #pragma unroll
    for (int j = 0; j < 8; ++j) r[j] = __fmul_rn(x[j], x[j]);
    #pragma unroll
    for (int i = 8; i < 64; i += 8) {
        #pragma unroll
        for (int j = 0; j < 8; ++j)
            r[j] = __fadd_rn(r[j], __fmul_rn(x[i + j], x[i + j]));
    }
    float l = __fadd_rn(__fadd_rn(r[0], r[1]), __fadd_rn(r[2], r[3]));
    float h = __fadd_rn(__fadd_rn(r[4], r[5]), __fadd_rn(r[6], r[7]));
    return __fadd_rn(l, h);
}

// fused prep: bf16 hi/lo codebook image + b2 (first 512) + accumulator zeroing
__global__ __launch_bounds__(256) void vq_prep(const float* __restrict__ ew,
                                               float* __restrict__ wsf,
                                               short* __restrict__ img) {
    int gt = blockIdx.x * 256 + threadIdx.x;   // 0..8191
    int c = gt >> 9, s = gt & 511;
    int grp = s >> 6, l = s & 63;
    int plane = grp >> 2, f = (grp >> 1) & 1, sub = grp & 1;
    int k  = c * 32 + sub * 16 + (l & 15);
    int d0 = f * 32 + (l >> 4) * 8;
    const float* p = ew + (size_t)k * D + d0;
    short8 v;
    #pragma unroll
    for (int j = 0; j < 8; ++j) {
        float x = p[j];
        short hs = f2bf(x);
        v[j] = plane ? f2bf(__fsub_rn(x, bf2f(hs))) : hs;
    }
    *(short8*)(img + (size_t)gt * 8) = v;

    if (gt < 516) wsf[512 + gt] = 0.0f;        // S, counts, nflag, ticket

    if (gt < K) {                              // numpy-exact sum(e^2)
        float row[D];
        const float* q = ew + (size_t)gt * D;
        #pragma unroll
        for (int d = 0; d < D; ++d) row[d] = q[d];
        wsf[gt] = np_sumsq64(row);
    }
}

// MFMA screen — r23 hot loop with ONE change: sec update via v_med3
// (sec' = med3(sc, best, sec) given sec<=best — bitwise-identical logic,
// one VALU op instead of two on the 64-iteration select chain).
__global__ __launch_bounds__(SBLK, 4) void vq_screen(
    const float* __restrict__ z, const float* __restrict__ ew,
    const short* __restrict__ img, const float* __restrict__ b2,
    float* __restrict__ out, float* __restrict__ S, int* __restrict__ gcnt,
    int* __restrict__ nflag, int* __restrict__ flist)
{
    extern __shared__ short lbuf[];            // 32768 shorts = 64KB dynamic
    __shared__ float s_mhb2[K];                // -0.5*||e||^2
    __shared__ int   s_cnt[K];

    const int tid  = threadIdx.x;
    const int lane = tid & 63;
    const int col  = lane & 15, g = lane >> 4; // token-col / k-group
    const int tbase = blockIdx.x * TPB + (tid >> 6) * 32;

    s_cnt[tid]  = 0;
    s_mhb2[tid] = -0.5f * b2[tid];

#define STAGE_HALF(h) do {                                                   \
        _Pragma("unroll")                                                    \
        for (int i_ = 0; i_ < 8; ++i_) {                                     \
            int idx_ = i_ * SBLK + tid;                                      \
            short8 v_ = *(const short8*)(img + ((size_t)(h) * 4096 + idx_) * 8); \
            *(short8*)&lbuf[(size_t)idx_ * 8] = v_;                          \
        }                                                                    \
    } while (0)

    STAGE_HALF(0);                             // loads in flight early

    // ---- B-frags: this wave's 32 tokens, hi/lo bf16, plus sum z^2 slices ----
    short8 zhi[2][2], zlo[2][2];
    float zss = 0.f;
    #pragma unroll
    for (int t = 0; t < 2; ++t) {
        const f32x4* zr = (const f32x4*)(z + (size_t)(tbase + t * 16 + col) * D);
        #pragma unroll
        for (int f = 0; f < 2; ++f) {
            f32x4 va = zr[f * 8 + g * 2], vb = zr[f * 8 + g * 2 + 1];
            float v[8] = {va[0], va[1], va[2], va[3], vb[0], vb[1], vb[2], vb[3]};
            short8 h8, l8;
            #pragma unroll
            for (int j = 0; j < 8; ++j) {
                float x = v[j];
                short hs = f2bf(x);
                h8[j] = hs;
                l8[j] = f2bf(__fsub_rn(x, bf2f(hs)));
                zss = fmaf(x, x, zss);
            }
            zhi[t][f] = h8; zlo[t][f] = l8;
        }
    }

    // 8 independent argmax sets [tile][r]
    float best[2][4], sec[2][4];
    int   kk[2][4];
    #pragma unroll
    for (int t = 0; t < 2; ++t)
        #pragma unroll
        for (int r = 0; r < 4; ++r) { best[t][r] = -1e30f; sec[t][r] = -1e30f; kk[t][r] = 0; }

#define COMPUTE_HALF(h) do {                                                 \
        _Pragma("unroll 2")                                                  \
        for (int c8_ = 0; c8_ < 8; ++c8_) {                                  \
            const short* bp_ = &lbuf[(c8_ * 512 + lane) * 8];                \
            _Pragma("unroll")                                                \
            for (int sub_ = 0; sub_ < 2; ++sub_) {                           \
                short8 ah0_ = *(const short8*)(bp_ + (0 + sub_) * 512);      \
                short8 ah1_ = *(const short8*)(bp_ + (2 + sub_) * 512);      \
                short8 al0_ = *(const short8*)(bp_ + (4 + sub_) * 512);      \
                short8 al1_ = *(const short8*)(bp_ + (6 + sub_) * 512);      \
                const int c0_ = ((h) * 8 + c8_) * 32 + sub_ * 16 + g * 4;    \
                f32x4 mhb_ = *(const f32x4*)&s_mhb2[c0_];                    \
                _Pragma("unroll")                                            \
                for (int t_ = 0; t_ < 2; ++t_) {                             \
                    f32x4 a1_ = mhb_;            /* chain1: dims 0-31  */    \
                    f32x4 a2_ = (f32x4){0.f, 0.f, 0.f, 0.f}; /* 32-63 */     \
                    a1_ = mfma16(ah0_, zhi[t_][0], a1_);                     \
                    a2_ = mfma16(ah1_, zhi[t_][1], a2_);                     \
                    a1_ = mfma16(ah0_, zlo[t_][0], a1_);                     \
                    a2_ = mfma16(ah1_, zlo[t_][1], a2_);                     \
                    a1_ = mfma16(al0_, zhi[t_][0], a1_);                     \
                    a2_ = mfma16(al1_, zhi[t_][1], a2_);                     \
                    _Pragma("unroll")                                        \
                    for (int r_ = 0; r_ < 4; ++r_) {                         \
                        float sc_ = a1_[r_] + a2_[r_];                       \
                        bool  g_  = sc_ > best[t_][r_];                      \
                        sec[t_][r_]  = __builtin_amdgcn_fmed3f(sc_,          \
                                          best[t_][r_], sec[t_][r_]);        \
                        best[t_][r_] = fmaxf(best[t_][r_], sc_);             \
                        kk[t_][r_]   = g_ ? c0_ + r_ : kk[t_][r_];           \
                    }                                                        \
                }                                                            \
            }                                                                \
        }                                                                    \
    } while (0)

    __syncthreads();                           // half-0 + s_mhb2/s_cnt ready
    COMPUTE_HALF(0);
    __syncthreads();                           // all reads of half-0 done
    STAGE_HALF(1);
    __syncthreads();
    COMPUTE_HALF(1);
#undef STAGE_HALF
#undef COMPUTE_HALF

    // ---- merge the 4 r-sets per tile (exact ties -> gap 0 -> flagged) ----
    float b1[2], b2s[2];
    int   k1[2];
#define MERGE2(bx, sx, kx, by, sy, ky, bo, so, ko) do {                      \
        if ((by) > (bx)) { bo = (by); so = fmaxf((bx), (sy)); ko = (ky); }   \
        else             { bo = (bx); so = fmaxf((by), (sx)); ko = (kx); }   \
    } while (0)
    #pragma unroll
    for (int t = 0; t < 2; ++t) {
        float bA, sA, bB, sB; int kA, kB;
        MERGE2(best[t][0], sec[t][0], kk[t][0], best[t][1], sec[t][1], kk[t][1], bA, sA, kA);
        MERGE2(best[t][2], sec[t][2], kk[t][2], best[t][3], sec[t][3], kk[t][3], bB, sB, kB);
        MERGE2(bA, sA, kA, bB, sB, kB, b1[t], b2s[t], k1[t]);
    }
#undef MERGE2

    // ---- cross-lane merge over the 4 k-groups (xor butterfly) ----
    #pragma unroll
    for (int t = 0; t < 2; ++t) {
        #pragma unroll
        for (int m = 16; m < 64; m <<= 1) {
            float ob = __shfl_xor(b1[t], m);
            float os = __shfl_xor(b2s[t], m);
            int   ok = __shfl_xor(k1[t], m);
            if (ob > b1[t])       { b2s[t] = fmaxf(b1[t], os); b1[t] = ob; k1[t] = ok; }
            else if (ob == b1[t]) { b2s[t] = b1[t]; if (ok < k1[t]) k1[t] = ok; }  // tie -> flag
            else                  { b2s[t] = fmaxf(b2s[t], ob); }
        }
    }

    // ---- enc + flags (lane<16) ----
    if (lane < 16) {
        #pragma unroll
        for (int t = 0; t < 2; ++t) {
            const int tok = tbase + t * 16 + col;
            out[ENC_OFF + tok] = (float)k1[t];
            atomicAdd(&s_cnt[k1[t]], 1);
            if (b1[t] - b2s[t] < EPS) {        // ambiguous: exact re-check
                int slot = atomicAdd(nflag, 1);
                if (slot < FLAG_CAP) flist[slot] = tok;
            }
        }
    }

    // ---- quantized_st = e row (error vs fl(z+fl(e-z)) ~ 6e-7 << 10.24) ----
    #pragma unroll
    for (int t = 0; t < 2; ++t) {
        const int tok = tbase + t * 16 + col;
        const f32x4* er4 = (const f32x4*)(ew + (size_t)k1[t] * D);
        f32x4* op = (f32x4*)(out + Q_OFF + (size_t)tok * D);
        #pragma unroll
        for (int f = 0; f < 2; ++f) {
            op[f * 8 + g * 2]     = er4[f * 8 + g * 2];
            op[f * 8 + g * 2 + 1] = er4[f * 8 + g * 2 + 1];
        }
    }

    // S = sum ||z||^2 - 2 * sum best_score (loss/mind thresholds are huge)
    float contrib = zss + ((lane < 16) ? -2.f * (b1[0] + b1[1]) : 0.f);
    #pragma unroll
    for (int off = 32; off; off >>= 1) contrib += __shfl_down(contrib, off);
    if (lane == 0) atomicAdd(S, contrib);

    __syncthreads();
    int cc = s_cnt[tid];
    if (cc) atomicAdd(&gcnt[tid], cc);
}

// exact numpy-f32 rescan (stride loop over flagged tokens) + fused finale:
// every block increments a ticket after a fence; the LAST block computes
// loss/perplexity/min_distance (all other blocks' gcnt atomics are visible
// by the release/acquire pairing of threadfence + device-scope atomicAdd).
__global__ __launch_bounds__(64) void vq_refine(
    const float* __restrict__ z, const float* __restrict__ ew,
    const float* __restrict__ b2, float* __restrict__ out,
    int* __restrict__ gcnt, const int* __restrict__ nflag,
    const int* __restrict__ flist, int* __restrict__ ticket,
    const float* __restrict__ S)
{
    int nf = *nflag; if (nf > FLAG_CAP) nf = FLAG_CAP;
    const int lane = threadIdx.x;

    for (int i = blockIdx.x; i < nf; i += RBLKS) {
        const int tok = flist[i];
        const int old = (int)out[ENC_OFF + tok];   // read before any write

        const f32x4* zr4 = (const f32x4*)(z + (size_t)tok * D);
        f32x4 zq[16];
        #pragma unroll
        for (int q = 0; q < 16; ++q) zq[q] = zr4[q];

        // a_n in numpy's exact f32 order (d ascending, 8-accumulator pattern)
        float ra[8];
        #pragma unroll
        for (int q = 0; q < 16; ++q) {
            #pragma unroll
            for (int rr = 0; rr < 4; ++rr) {
                int j = (q & 1) * 4 + rr;
                float x = zq[q][rr];
                if (q < 2) ra[j] = __fmul_rn(x, x);
                else       ra[j] = __fadd_rn(ra[j], __fmul_rn(x, x));
            }
        }
        float lsum = __fadd_rn(__fadd_rn(ra[0], ra[1]), __fadd_rn(ra[2], ra[3]));
        float hsum = __fadd_rn(__fadd_rn(ra[4], ra[5]), __fadd_rn(ra[6], ra[7]));
        const float an = __fadd_rn(lsum, hsum);

        float bd = 1e30f; int bk = 0;
        #pragma unroll 1
        for (int j = 0; j < 8; ++j) {
            const int cc = j * 64 + lane;
            const f32x4* er4 = (const f32x4*)(ew + (size_t)cc * D);
            float gacc = 0.f;
            #pragma unroll
            for (int q = 0; q < 16; ++q) {
                f32x4 ev = er4[q];
                #pragma unroll
                for (int rr = 0; rr < 4; ++rr) gacc = fmaf(zq[q][rr], ev[rr], gacc);
            }
            float dd = fmaf(-2.f, gacc, __fadd_rn(an, b2[cc]));
            if (dd < bd) { bd = dd; bk = cc; }     // lane-ascending codes
        }
        #pragma unroll
        for (int off = 32; off; off >>= 1) {       // min-d, min-index
            float obd = __shfl_down(bd, off);
            int   obk = __shfl_down(bk, off);
            if (obd < bd || (obd == bd && obk < bk)) { bd = obd; bk = obk; }
        }
        bk = __shfl(bk, 0);

        if (bk != old) {
            out[Q_OFF + (size_t)tok * D + lane] = ew[(size_t)bk * D + lane];
            if (lane == 0) {
                out[ENC_OFF + tok] = (float)bk;
                atomicAdd(&gcnt[bk], 1);
                atomicAdd(&gcnt[old], -1);
            }
        }
    }

    // ---- last-block finale ----
    __threadfence();                               // release this block's writes
    int tk = 0;
    if (lane == 0) tk = atomicAdd(ticket, 1);
    tk = __shfl(tk, 0);
    if (tk == RBLKS - 1) {                         // all other blocks done
        float term = 0.f;
        #pragma unroll
        for (int j = 0; j < 8; ++j) {              // 8 codes per lane
            float p = (float)gcnt[j * 64 + lane] * (1.f / (float)N_TOK);
            term += p * logf(p + 1e-10f);
        }
        #pragma unroll
        for (int off = 32; off; off >>= 1) term += __shfl_down(term, off);
        if (lane == 0) {
            float Sv = S[0];
            out[PERP_OFF] = expf(-term);
            out[LOSS_OFF] = 1.25f * Sv * (1.f / (float)(N_TOK * D));
            out[MIND_OFF] = Sv * (1.f / (float)N_TOK);
        }
    }
}

extern "C" void kernel_launch(void* const* d_in, const int* in_sizes, int n_in,
                              void* d_out, int out_size, void* d_ws, size_t ws_size,
                              hipStream_t stream)
{
    const float* z  = (const float*)d_in[0];
    const float* ew = (const float*)d_in[1];
    float* out = (float*)d_out;
    float* wsf = (float*)d_ws;

    float* Sp     = wsf + 512;
    int*   gcnt   = (int*)(wsf + 514);
    int*   nflag  = (int*)(wsf + 1026);
    int*   ticket = (int*)(wsf + 1027);
    int*   flist  = (int*)(wsf + 1028);
    short* img    = (short*)(wsf + 16384);   // 128 KB bf16 image

    // allow 64KB dynamic LDS for vq_screen (idempotent, capture-safe)
    hipFuncSetAttribute((const void*)vq_screen,
                        hipFuncAttributeMaxDynamicSharedMemorySize, 65536);

    // prep zeroes the accumulators itself (graph replays don't re-poison)
    vq_prep  <<<32, 256, 0, stream>>>(ew, wsf, img);
    vq_screen<<<N_TOK / TPB, SBLK, 65536, stream>>>(z, ew, img, wsf, out, Sp,
                                                    gcnt, nflag, flist);
    vq_refine<<<RBLKS, 64, 0, stream>>>(z, ew, wsf, out, gcnt, nflag, flist,
                                        ticket, Sp);
}

// Round 25
// 100.390 us; speedup vs baseline: 1.1311x; 1.1311x over previous
//
#include <hip/hip_runtime.h>
#include <math.h>

#define D 64
#define K 512
#define N_TOK (32 * 4096)            // 131072 tokens
#define SBLK 512                     // screen threads (8 waves)
#define TPB 256                      // tokens per block (8 waves x 32)
#define EPS 1e-5f                    // screen ambiguity margin (err bound ~5e-7, 20x)
#define FLAG_CAP 8192

// output layout (all f32, concatenated in reference return order)
#define Q_OFF    0
#define LOSS_OFF 8388608
#define PERP_OFF 8388609
#define ENC_OFF  8388610
#define MIND_OFF 8519682

// ws layout (floats): [0..511] b2 ; [512] S ; [514..1025] counts(int) ;
// [1026] nflag(int) ; [1028..1028+FLAG_CAP) flist(int) ;
// [16384..] bf16 codebook image, 65536 shorts = 128 KB (ws >= 192 KB).
// img: chunk c (32 codes) = 512 slots x 16B, slot s = grp*64 + lane,
//   grp = plane*4 + f*2 + sub; slot holds codes k=c*32+sub*16+(lane&15),
//   dims f*32+(lane>>4)*8 .. +8, hi (plane0) or lo (plane1) bf16.

typedef __attribute__((ext_vector_type(8))) short  short8;   // 8 bf16 (4 VGPR)
typedef __attribute__((ext_vector_type(4))) float  f32x4;

__device__ __forceinline__ short f2bf(float x) {             // RNE f32->bf16 bits
    unsigned u = __builtin_bit_cast(unsigned, x);
    unsigned r = (u + 0x7fffu + ((u >> 16) & 1u)) >> 16;
    return (short)r;
}
__device__ __forceinline__ float bf2f(short s) {
    unsigned u = ((unsigned)(unsigned short)s) << 16;
    return __builtin_bit_cast(float, u);
}
__device__ __forceinline__ f32x4 mfma16(short8 a, short8 b, f32x4 c) {
    return __builtin_amdgcn_mfma_f32_16x16x32_bf16(a, b, c, 0, 0, 0);
}

// numpy pairwise_sum, n=64, scalar 8-accumulator order on fl(x*x)
__device__ __forceinline__ float np_sumsq64(const float* x) {
    float r[8];
    #pragma unroll
    for (int j = 0; j < 8; ++j) r[j] = __fmul_rn(x[j], x[j]);
    #pragma unroll
    for (int i = 8; i < 64; i += 8) {
        #pragma unroll
        for (int j = 0; j < 8; ++j)
            r[j] = __fadd_rn(r[j], __fmul_rn(x[i + j], x[i + j]));
    }
    float l = __fadd_rn(__fadd_rn(r[0], r[1]), __fadd_rn(r[2], r[3]));
    float h = __fadd_rn(__fadd_rn(r[4], r[5]), __fadd_rn(r[6], r[7]));
    return __fadd_rn(l, h);
}

// fused prep: bf16 hi/lo codebook image + b2 (first 512) + accumulator zeroing
__global__ __launch_bounds__(256) void vq_prep(const float* __restrict__ ew,
                                               float* __restrict__ wsf,
                                               short* __restrict__ img) {
    int gt = blockIdx.x * 256 + threadIdx.x;   // 0..8191
    int c = gt >> 9, s = gt & 511;
    int grp = s >> 6, l = s & 63;
    int plane = grp >> 2, f = (grp >> 1) & 1, sub = grp & 1;
    int k  = c * 32 + sub * 16 + (l & 15);
    int d0 = f * 32 + (l >> 4) * 8;
    const float* p = ew + (size_t)k * D + d0;
    short8 v;
    #pragma unroll
    for (int j = 0; j < 8; ++j) {
        float x = p[j];
        short hs = f2bf(x);
        v[j] = plane ? f2bf(__fsub_rn(x, bf2f(hs))) : hs;
    }
    *(short8*)(img + (size_t)gt * 8) = v;

    if (gt < 516) wsf[512 + gt] = 0.0f;        // S, counts, nflag (re-zero per call)

    if (gt < K) {                              // numpy-exact sum(e^2)
        float row[D];
        const float* q = ew + (size_t)gt * D;
        #pragma unroll
        for (int d = 0; d < D; ++d) row[d] = q[d];
        wsf[gt] = np_sumsq64(row);
    }
}

// MFMA screen — r23 structure (101.7 us bench best) + med3 sec-update
// (measured neutral-positive in r24: 83.0 vs 84.5). Hot loop otherwise
// byte-identical: half-codebook LDS staging, 3 barriers, 4 independent
// 3-MFMA chains + 8 independent argmax sets per sub, (512,4) no-spill.
__global__ __launch_bounds__(SBLK, 4) void vq_screen(
    const float* __restrict__ z, const float* __restrict__ ew,
    const short* __restrict__ img, const float* __restrict__ b2,
    float* __restrict__ out, float* __restrict__ S, int* __restrict__ gcnt,
    int* __restrict__ nflag, int* __restrict__ flist)
{
    extern __shared__ short lbuf[];            // 32768 shorts = 64KB dynamic
    __shared__ float s_mhb2[K];                // -0.5*||e||^2
    __shared__ int   s_cnt[K];

    const int tid  = threadIdx.x;
    const int lane = tid & 63;
    const int col  = lane & 15, g = lane >> 4; // token-col / k-group
    const int tbase = blockIdx.x * TPB + (tid >> 6) * 32;

    s_cnt[tid]  = 0;
    s_mhb2[tid] = -0.5f * b2[tid];

#define STAGE_HALF(h) do {                                                   \
        _Pragma("unroll")                                                    \
        for (int i_ = 0; i_ < 8; ++i_) {                                     \
            int idx_ = i_ * SBLK + tid;                                      \
            short8 v_ = *(const short8*)(img + ((size_t)(h) * 4096 + idx_) * 8); \
            *(short8*)&lbuf[(size_t)idx_ * 8] = v_;                          \
        }                                                                    \
    } while (0)

    STAGE_HALF(0);                             // loads in flight early

    // ---- B-frags: this wave's 32 tokens, hi/lo bf16, plus sum z^2 slices ----
    short8 zhi[2][2], zlo[2][2];
    float zss = 0.f;
    #pragma unroll
    for (int t = 0; t < 2; ++t) {
        const f32x4* zr = (const f32x4*)(z + (size_t)(tbase + t * 16 + col) * D);
        #pragma unroll
        for (int f = 0; f < 2; ++f) {
            f32x4 va = zr[f * 8 + g * 2], vb = zr[f * 8 + g * 2 + 1];
            float v[8] = {va[0], va[1], va[2], va[3], vb[0], vb[1], vb[2], vb[3]};
            short8 h8, l8;
            #pragma unroll
            for (int j = 0; j < 8; ++j) {
                float x = v[j];
                short hs = f2bf(x);
                h8[j] = hs;
                l8[j] = f2bf(__fsub_rn(x, bf2f(hs)));
                zss = fmaf(x, x, zss);
            }
            zhi[t][f] = h8; zlo[t][f] = l8;
        }
    }

    // 8 independent argmax sets [tile][r]
    float best[2][4], sec[2][4];
    int   kk[2][4];
    #pragma unroll
    for (int t = 0; t < 2; ++t)
        #pragma unroll
        for (int r = 0; r < 4; ++r) { best[t][r] = -1e30f; sec[t][r] = -1e30f; kk[t][r] = 0; }

#define COMPUTE_HALF(h) do {                                                 \
        _Pragma("unroll 2")                                                  \
        for (int c8_ = 0; c8_ < 8; ++c8_) {                                  \
            const short* bp_ = &lbuf[(c8_ * 512 + lane) * 8];                \
            _Pragma("unroll")                                                \
            for (int sub_ = 0; sub_ < 2; ++sub_) {                           \
                short8 ah0_ = *(const short8*)(bp_ + (0 + sub_) * 512);      \
                short8 ah1_ = *(const short8*)(bp_ + (2 + sub_) * 512);      \
                short8 al0_ = *(const short8*)(bp_ + (4 + sub_) * 512);      \
                short8 al1_ = *(const short8*)(bp_ + (6 + sub_) * 512);      \
                const int c0_ = ((h) * 8 + c8_) * 32 + sub_ * 16 + g * 4;    \
                f32x4 mhb_ = *(const f32x4*)&s_mhb2[c0_];                    \
                _Pragma("unroll")                                            \
                for (int t_ = 0; t_ < 2; ++t_) {                             \
                    f32x4 a1_ = mhb_;            /* chain1: dims 0-31  */    \
                    f32x4 a2_ = (f32x4){0.f, 0.f, 0.f, 0.f}; /* 32-63 */     \
                    a1_ = mfma16(ah0_, zhi[t_][0], a1_);                     \
                    a2_ = mfma16(ah1_, zhi[t_][1], a2_);                     \
                    a1_ = mfma16(ah0_, zlo[t_][0], a1_);                     \
                    a2_ = mfma16(ah1_, zlo[t_][1], a2_);                     \
                    a1_ = mfma16(al0_, zhi[t_][0], a1_);                     \
                    a2_ = mfma16(al1_, zhi[t_][1], a2_);                     \
                    _Pragma("unroll")                                        \
                    for (int r_ = 0; r_ < 4; ++r_) {                         \
                        float sc_ = a1_[r_] + a2_[r_];                       \
                        bool  g_  = sc_ > best[t_][r_];                      \
                        sec[t_][r_]  = __builtin_amdgcn_fmed3f(sc_,          \
                                          best[t_][r_], sec[t_][r_]);        \
                        best[t_][r_] = fmaxf(best[t_][r_], sc_);             \
                        kk[t_][r_]   = g_ ? c0_ + r_ : kk[t_][r_];           \
                    }                                                        \
                }                                                            \
            }                                                                \
        }                                                                    \
    } while (0)

    __syncthreads();                           // half-0 + s_mhb2/s_cnt ready
    COMPUTE_HALF(0);
    __syncthreads();                           // all reads of half-0 done
    STAGE_HALF(1);
    __syncthreads();
    COMPUTE_HALF(1);
#undef STAGE_HALF
#undef COMPUTE_HALF

    // ---- merge the 4 r-sets per tile (exact ties -> gap 0 -> flagged) ----
    float b1[2], b2s[2];
    int   k1[2];
#define MERGE2(bx, sx, kx, by, sy, ky, bo, so, ko) do {                      \
        if ((by) > (bx)) { bo = (by); so = fmaxf((bx), (sy)); ko = (ky); }   \
        else             { bo = (bx); so = fmaxf((by), (sx)); ko = (kx); }   \
    } while (0)
    #pragma unroll
    for (int t = 0; t < 2; ++t) {
        float bA, sA, bB, sB; int kA, kB;
        MERGE2(best[t][0], sec[t][0], kk[t][0], best[t][1], sec[t][1], kk[t][1], bA, sA, kA);
        MERGE2(best[t][2], sec[t][2], kk[t][2], best[t][3], sec[t][3], kk[t][3], bB, sB, kB);
        MERGE2(bA, sA, kA, bB, sB, kB, b1[t], b2s[t], k1[t]);
    }
#undef MERGE2

    // ---- cross-lane merge over the 4 k-groups (xor butterfly) ----
    #pragma unroll
    for (int t = 0; t < 2; ++t) {
        #pragma unroll
        for (int m = 16; m < 64; m <<= 1) {
            float ob = __shfl_xor(b1[t], m);
            float os = __shfl_xor(b2s[t], m);
            int   ok = __shfl_xor(k1[t], m);
            if (ob > b1[t])       { b2s[t] = fmaxf(b1[t], os); b1[t] = ob; k1[t] = ok; }
            else if (ob == b1[t]) { b2s[t] = b1[t]; if (ok < k1[t]) k1[t] = ok; }  // tie -> flag
            else                  { b2s[t] = fmaxf(b2s[t], ob); }
        }
    }

    // ---- enc + flags (lane<16) ----
    if (lane < 16) {
        #pragma unroll
        for (int t = 0; t < 2; ++t) {
            const int tok = tbase + t * 16 + col;
            out[ENC_OFF + tok] = (float)k1[t];
            atomicAdd(&s_cnt[k1[t]], 1);
            if (b1[t] - b2s[t] < EPS) {        // ambiguous: exact re-check
                int slot = atomicAdd(nflag, 1);
                if (slot < FLAG_CAP) flist[slot] = tok;
            }
        }
    }

    // ---- quantized_st = e row (error vs fl(z+fl(e-z)) ~ 6e-7 << 10.24) ----
    #pragma unroll
    for (int t = 0; t < 2; ++t) {
        const int tok = tbase + t * 16 + col;
        const f32x4* er4 = (const f32x4*)(ew + (size_t)k1[t] * D);
        f32x4* op = (f32x4*)(out + Q_OFF + (size_t)tok * D);
        #pragma unroll
        for (int f = 0; f < 2; ++f) {
            op[f * 8 + g * 2]     = er4[f * 8 + g * 2];
            op[f * 8 + g * 2 + 1] = er4[f * 8 + g * 2 + 1];
        }
    }

    // S = sum ||z||^2 - 2 * sum best_score (loss/mind thresholds are huge)
    float contrib = zss + ((lane < 16) ? -2.f * (b1[0] + b1[1]) : 0.f);
    #pragma unroll
    for (int off = 32; off; off >>= 1) contrib += __shfl_down(contrib, off);
    if (lane == 0) atomicAdd(S, contrib);

    __syncthreads();
    int cc = s_cnt[tid];
    if (cc) atomicAdd(&gcnt[tid], cc);
}

// exact numpy-f32 rescan: ONE 64-thread block per flagged token; blocks
// beyond nflag exit immediately (grid = FLAG_CAP). Repairs enc/hist/Q row.
__global__ __launch_bounds__(64) void vq_refine(
    const float* __restrict__ z, const float* __restrict__ ew,
    const float* __restrict__ b2, float* __restrict__ out,
    int* __restrict__ gcnt, const int* __restrict__ nflag,
    const int* __restrict__ flist)
{
    int nf = *nflag; if (nf > FLAG_CAP) nf = FLAG_CAP;
    if ((int)blockIdx.x >= nf) return;
    const int lane = threadIdx.x;
    const int tok  = flist[blockIdx.x];
    const int old  = (int)out[ENC_OFF + tok];  // read before any write

    const f32x4* zr4 = (const f32x4*)(z + (size_t)tok * D);
    f32x4 zq[16];
    #pragma unroll
    for (int q = 0; q < 16; ++q) zq[q] = zr4[q];

    // a_n in numpy's exact f32 order (d ascending, 8-accumulator pattern)
    float ra[8];
    #pragma unroll
    for (int q = 0; q < 16; ++q) {
        #pragma unroll
        for (int rr = 0; rr < 4; ++rr) {
            int j = (q & 1) * 4 + rr;
            float x = zq[q][rr];
            if (q < 2) ra[j] = __fmul_rn(x, x);
            else       ra[j] = __fadd_rn(ra[j], __fmul_rn(x, x));
        }
    }
    float lsum = __fadd_rn(__fadd_rn(ra[0], ra[1]), __fadd_rn(ra[2], ra[3]));
    float hsum = __fadd_rn(__fadd_rn(ra[4], ra[5]), __fadd_rn(ra[6], ra[7]));
    const float an = __fadd_rn(lsum, hsum);

    float bd = 1e30f; int bk = 0;
    #pragma unroll 1
    for (int j = 0; j < 8; ++j) {
        const int cc = j * 64 + lane;
        const f32x4* er4 = (const f32x4*)(ew + (size_t)cc * D);
        float gacc = 0.f;
        #pragma unroll
        for (int q = 0; q < 16; ++q) {
            f32x4 ev = er4[q];
            #pragma unroll
            for (int rr = 0; rr < 4; ++rr) gacc = fmaf(zq[q][rr], ev[rr], gacc);
        }
        float dd = fmaf(-2.f, gacc, __fadd_rn(an, b2[cc]));
        if (dd < bd) { bd = dd; bk = cc; }     // lane-ascending codes
    }
    #pragma unroll
    for (int off = 32; off; off >>= 1) {       // min-d, min-index
        float obd = __shfl_down(bd, off);
        int   obk = __shfl_down(bk, off);
        if (obd < bd || (obd == bd && obk < bk)) { bd = obd; bk = obk; }
    }
    bk = __shfl(bk, 0);

    if (bk != old) {
        out[Q_OFF + (size_t)tok * D + lane] = ew[(size_t)bk * D + lane];
        if (lane == 0) {
            out[ENC_OFF + tok] = (float)bk;
            atomicAdd(&gcnt[bk], 1);
            atomicAdd(&gcnt[old], -1);
        }
    }
}

__global__ void vq_fin(const float* __restrict__ S, const int* __restrict__ gcnt,
                       float* __restrict__ out)
{
    __shared__ float red[8];
    int t = threadIdx.x;               // 512 threads, one per code
    float p = (float)gcnt[t] * (1.f / (float)N_TOK);
    float term = p * logf(p + 1e-10f);
    #pragma unroll
    for (int off = 32; off; off >>= 1) term += __shfl_down(term, off);
    if ((t & 63) == 0) red[t >> 6] = term;
    __syncthreads();
    if (t == 0) {
        float s = 0.f;
        #pragma unroll
        for (int i = 0; i < 8; ++i) s += red[i];
        float Sv = S[0];
        out[PERP_OFF] = expf(-s);
        out[LOSS_OFF] = 1.25f * Sv * (1.f / (float)(N_TOK * D));
        out[MIND_OFF] = Sv * (1.f / (float)N_TOK);
    }
}

extern "C" void kernel_launch(void* const* d_in, const int* in_sizes, int n_in,
                              void* d_out, int out_size, void* d_ws, size_t ws_size,
                              hipStream_t stream)
{
    const float* z  = (const float*)d_in[0];
    const float* ew = (const float*)d_in[1];
    float* out = (float*)d_out;
    float* wsf = (float*)d_ws;

    float* Sp    = wsf + 512;
    int*   gcnt  = (int*)(wsf + 514);
    int*   nflag = (int*)(wsf + 1026);
    int*   flist = (int*)(wsf + 1028);
    short* img   = (short*)(wsf + 16384);    // 128 KB bf16 image

    // allow 64KB dynamic LDS for vq_screen (idempotent, capture-safe)
    hipFuncSetAttribute((const void*)vq_screen,
                        hipFuncAttributeMaxDynamicSharedMemorySize, 65536);

    // prep zeroes the accumulators itself (graph replays don't re-poison)
    vq_prep  <<<32, 256, 0, stream>>>(ew, wsf, img);
    vq_screen<<<N_TOK / TPB, SBLK, 65536, stream>>>(z, ew, img, wsf, out, Sp,
                                                    gcnt, nflag, flist);
    vq_refine<<<FLAG_CAP, 64, 0, stream>>>(z, ew, wsf, out, gcnt, nflag, flist);
    vq_fin   <<<1, 512, 0, stream>>>(Sp, gcnt, out);
}